// Round 17
// baseline (292.778 us; speedup 1.0000x reference)
//
#include <hip/hip_runtime.h>
#include <hip/hip_bf16.h>

constexpr int BATCH = 4, SEQLEN = 2048, DM = 1024, DI = 2048, DS = 16, DC = 4, DTR = 64;
constexpr int M = BATCH * SEQLEN;      // 8192
constexpr int NXZ = 2 * DI;            // 4096
constexpr int NXDBL = DTR + 2 * DS;    // 96
constexpr size_t CS = (size_t)BATCH * DI * DS;  // per-chunk state stride (131072)
constexpr float L2E = 1.44269504088896f;

typedef __attribute__((ext_vector_type(8))) short short8;
typedef __attribute__((ext_vector_type(4))) float f32x4;
typedef __attribute__((ext_vector_type(2))) float f32x2;

__device__ __forceinline__ float fexp2(float x) { return __builtin_amdgcn_exp2f(x); }
__device__ __forceinline__ float frcp(float x) { return __builtin_amdgcn_rcpf(x); }
__device__ __forceinline__ float fsig(float z) {
  return frcp(1.f + fexp2(-L2E * z));
}
__device__ __forceinline__ float softplus_fast(float x) {
  return (x > 20.f) ? x
                    : 0.693147180559945f * __builtin_amdgcn_logf(1.f + fexp2(x * L2E));
}

// async global->LDS, 16B per lane; LDS dest wave-uniform base (+lane*16 HW).
__device__ __forceinline__ void load_lds16(const void* g, void* l) {
  __builtin_amdgcn_global_load_lds(
      (const __attribute__((address_space(1))) unsigned int*)g,
      (__attribute__((address_space(3))) unsigned int*)l, 16, 0, 0);
}

// ---------- merged 5-buffer f32 -> bf16 convert (8 elems/thread, 16B stores) ----------
__global__ __launch_bounds__(256) void k_cvt5(const float* __restrict__ p0, int n0, __hip_bfloat16* __restrict__ q0,
                                              const float* __restrict__ p1, int n1, __hip_bfloat16* __restrict__ q1,
                                              const float* __restrict__ p2, int n2, __hip_bfloat16* __restrict__ q2,
                                              const float* __restrict__ p3, int n3, __hip_bfloat16* __restrict__ q3,
                                              const float* __restrict__ p4, int n4, __hip_bfloat16* __restrict__ q4) {
  int i = (blockIdx.x * 256 + threadIdx.x) * 8;
  const float* s;
  __hip_bfloat16* d;
  if (i < n0) { s = p0; d = q0; }
  else if ((i -= n0) < n1) { s = p1; d = q1; }
  else if ((i -= n1) < n2) { s = p2; d = q2; }
  else if ((i -= n2) < n3) { s = p3; d = q3; }
  else if ((i -= n3) < n4) { s = p4; d = q4; }
  else return;
  float4 v0 = *reinterpret_cast<const float4*>(s + i);
  float4 v1 = *reinterpret_cast<const float4*>(s + i + 4);
  unsigned short o[8];
  o[0] = __bfloat16_as_ushort(__float2bfloat16(v0.x));
  o[1] = __bfloat16_as_ushort(__float2bfloat16(v0.y));
  o[2] = __bfloat16_as_ushort(__float2bfloat16(v0.z));
  o[3] = __bfloat16_as_ushort(__float2bfloat16(v0.w));
  o[4] = __bfloat16_as_ushort(__float2bfloat16(v1.x));
  o[5] = __bfloat16_as_ushort(__float2bfloat16(v1.y));
  o[6] = __bfloat16_as_ushort(__float2bfloat16(v1.z));
  o[7] = __bfloat16_as_ushort(__float2bfloat16(v1.w));
  *reinterpret_cast<short8*>(d + i) = *reinterpret_cast<short8*>(o);
}

// ---------- prep: A2 = -exp(A_log)*log2e  AND conv-w transpose, one launch ----------
__global__ __launch_bounds__(256) void k_prep(const float* __restrict__ alog,
                                              float* __restrict__ an,
                                              const float* __restrict__ cw,
                                              float* __restrict__ cwt) {
  int i = blockIdx.x * 256 + threadIdx.x;
  if (i < DI * DS) {
    an[i] = -__expf(alog[i]) * L2E;
  } else {
    int j = i - DI * DS;
    if (j < DI * DC) {
      int d = j >> 2, w = j & 3;
      cwt[w * DI + d] = cw[j];
    }
  }
}

// ---------- pipelined 256xBN BK=64 bf16 NT GEMM, stages-at-top (verified best) ----------
template <int BN, int OUTMODE, bool SWZ>  // OUTMODE: 0=f32, 1=bf16
__global__ __launch_bounds__(512, 2) void k_gemmp(const __hip_bfloat16* __restrict__ A, int lda,
                                                  const __hip_bfloat16* __restrict__ Bm, int ldb,
                                                  void* __restrict__ Cp, int ldc, int K) {
  constexpr int BK = 64;
  constexpr int ASLOT = 16384;
  constexpr int BSLOT = BN * BK;
  constexpr int FN = (BN / 4) / 16;
  constexpr int BBASE = 2 * ASLOT;

  const int tid = threadIdx.x;
  const int wid = tid >> 6, l = tid & 63;
  const int wr = wid >> 2, wc = wid & 3;

  int bx = blockIdx.x, by = blockIdx.y;
  if constexpr (SWZ) {
    const int gx = gridDim.x;
    int nlin = by * gx + bx;
    const int nwg = gx * gridDim.y;
    nlin = (nlin & 7) * (nwg >> 3) + (nlin >> 3);
    by = nlin / gx; bx = nlin % gx;
  }
  const int bm0 = by * 256, bn0 = bx * BN;
  const int NT = K / BK;

  __shared__ short LDS[2 * (ASLOT + BSLOT)];

  const int gc8 = (l & 7) ^ ((l >> 3) & 7);
  const __hip_bfloat16* Abase = A + (size_t)(bm0 + wid * 8 + (l >> 3)) * lda + gc8 * 8;
  const __hip_bfloat16* Bbase = Bm + (size_t)(bn0 + wid * 8 + (l >> 3)) * ldb + gc8 * 8;
  const int wslot = wid * 512;

  const int c8k0 = ((l >> 4) ^ (l & 7)) * 8;
  const int c8k1 = ((4 + (l >> 4)) ^ (l & 7)) * 8;
  const int aoff0 = wr * 8192 + (l & 15) * 64;
  const int boff0 = BBASE + wc * (BN / 4) * 64 + (l & 15) * 64;

  f32x4 acc[8][FN] = {};

  auto stageA = [&](int s, int kt) {
#pragma unroll
    for (int g = 0; g < 4; g++)
      load_lds16(Abase + (size_t)(g * 64) * lda + kt * BK,
                 &LDS[s * ASLOT + g * 4096 + wslot]);
  };
  auto stageB = [&](int s, int kt) {
#pragma unroll
    for (int g = 0; g < BN / 64; g++)
      load_lds16(Bbase + (size_t)(g * 64) * ldb + kt * BK,
                 &LDS[BBASE + s * BSLOT + g * 4096 + wslot]);
  };

  stageA(0, 0); stageB(0, 0);

  for (int t = 0; t < NT; t++) {
    const int d = t & 1;
    asm volatile("s_waitcnt vmcnt(0)" ::: "memory");
    __builtin_amdgcn_s_barrier();
    if (t + 1 < NT) { stageA(d ^ 1, t + 1); stageB(d ^ 1, t + 1); }

    const int adb = d * ASLOT + aoff0;
    const int bdb = d * BSLOT + boff0;
    short8 a0[4][2], a1[4][2], b[FN][2];
#pragma unroll
    for (int i = 0; i < 4; i++) {
      a0[i][0] = *reinterpret_cast<const short8*>(&LDS[adb + i * 1024 + c8k0]);
      a0[i][1] = *reinterpret_cast<const short8*>(&LDS[adb + i * 1024 + c8k1]);
    }
#pragma unroll
    for (int j = 0; j < FN; j++) {
      b[j][0] = *reinterpret_cast<const short8*>(&LDS[bdb + j * 1024 + c8k0]);
      b[j][1] = *reinterpret_cast<const short8*>(&LDS[bdb + j * 1024 + c8k1]);
    }
#pragma unroll
    for (int i = 0; i < 4; i++) {
      a1[i][0] = *reinterpret_cast<const short8*>(&LDS[adb + (4 + i) * 1024 + c8k0]);
      a1[i][1] = *reinterpret_cast<const short8*>(&LDS[adb + (4 + i) * 1024 + c8k1]);
    }
#pragma unroll
    for (int i = 0; i < 4; i++)
#pragma unroll
      for (int j = 0; j < FN; j++)
#pragma unroll
        for (int ks = 0; ks < 2; ks++) {
          acc[i][j] = __builtin_amdgcn_mfma_f32_16x16x32_bf16(a0[i][ks], b[j][ks], acc[i][j], 0, 0, 0);
          acc[4 + i][j] = __builtin_amdgcn_mfma_f32_16x16x32_bf16(a1[i][ks], b[j][ks], acc[4 + i][j], 0, 0, 0);
        }
  }

  const int crow0 = bm0 + wr * 128 + (l >> 4) * 4;
  const int ccol0 = bn0 + wc * (BN / 4) + (l & 15);
#pragma unroll
  for (int im = 0; im < 8; im++)
#pragma unroll
    for (int jn = 0; jn < FN; jn++) {
      const int col = ccol0 + jn * 16;
#pragma unroll
      for (int r = 0; r < 4; r++) {
        const int row = crow0 + im * 16 + r;
        float v = acc[im][jn][r];
        if constexpr (OUTMODE == 0)
          reinterpret_cast<float*>(Cp)[(size_t)row * ldc + col] = v;
        else
          reinterpret_cast<__hip_bfloat16*>(Cp)[(size_t)row * ldc + col] = __float2bfloat16(v);
      }
    }
}

// ---------- bf16 NT GEMM, m97 structure ----------
template <int BM, int BN, int OUTMODE>
__global__ __launch_bounds__(256) void k_gemm_dl(const __hip_bfloat16* __restrict__ A, int lda,
                                                 const __hip_bfloat16* __restrict__ Bm, int ldb,
                                                 void* __restrict__ Cp, int ldc, int K,
                                                 const float* __restrict__ bias) {
  constexpr int BK = 32;
  constexpr int WM = BM / 2, WN = BN / 2;
  constexpr int FM = WM / 16, FN = WN / 16;

  const int tid = threadIdx.x;
  const int wid = tid >> 6, lane = tid & 63;
  const int wm = wid >> 1, wn = wid & 1;
  const int bm0 = blockIdx.y * BM, bn0 = blockIdx.x * BN;
  int kz = 0;
  if constexpr (OUTMODE == 4) kz = blockIdx.z;

  __shared__ short As[BM * BK];
  __shared__ short Bs[BN * BK];

  f32x4 acc[FM][FN] = {};

  const int lrow = lane & 15;
  const int lk = (lane >> 4) * 8;
  const int srow = wid * 16 + (lane >> 2);
  const int scol = (lane & 3) * 8;

  const __hip_bfloat16* Ag = &A[(size_t)(bm0 + srow) * lda + scol + (size_t)kz * K];
  const __hip_bfloat16* Bg = &Bm[(size_t)(bn0 + srow) * ldb + scol + (size_t)kz * K];

  for (int k0 = 0; k0 < K; k0 += BK) {
    __syncthreads();
#pragma unroll
    for (int i = 0; i < (BM + 63) / 64; i++)
      load_lds16(Ag + (size_t)i * 64 * lda + k0, &As[(i * 64 + wid * 16) * BK]);
#pragma unroll
    for (int i = 0; i < (BN + 63) / 64; i++)
      if ((BN % 64 == 0) || (i * 64 + wid * 16 < BN))
        load_lds16(Bg + (size_t)i * 64 * ldb + k0, &Bs[(i * 64 + wid * 16) * BK]);
    __syncthreads();

    short8 af[FM], bf[FN];
#pragma unroll
    for (int i = 0; i < FM; i++)
      af[i] = *reinterpret_cast<const short8*>(&As[(wm * WM + i * 16 + lrow) * BK + lk]);
#pragma unroll
    for (int j = 0; j < FN; j++)
      bf[j] = *reinterpret_cast<const short8*>(&Bs[(wn * WN + j * 16 + lrow) * BK + lk]);
#pragma unroll
    for (int i = 0; i < FM; i++)
#pragma unroll
      for (int j = 0; j < FN; j++)
        acc[i][j] = __builtin_amdgcn_mfma_f32_16x16x32_bf16(af[i], bf[j], acc[i][j], 0, 0, 0);
  }

  const int crow0 = bm0 + wm * WM + (lane >> 4) * 4;
  const int ccol0 = bn0 + wn * WN + lrow;
#pragma unroll
  for (int i = 0; i < FM; i++)
#pragma unroll
    for (int j = 0; j < FN; j++) {
      const int col = ccol0 + j * 16;
      float bv = 0.f;
      if constexpr (OUTMODE == 2) bv = bias[col];
#pragma unroll
      for (int r = 0; r < 4; r++) {
        const int row = crow0 + i * 16 + r;
        float v = acc[i][j][r];
        if constexpr (OUTMODE == 0) {
          reinterpret_cast<float*>(Cp)[(size_t)row * ldc + col] = v;
        } else if constexpr (OUTMODE == 2) {
          reinterpret_cast<__hip_bfloat16*>(Cp)[(size_t)row * ldc + col] =
              __float2bfloat16(softplus_fast(v + bv));
        } else {  // 4: split-K partial
          reinterpret_cast<float*>(Cp)[(size_t)kz * M * NXDBL + (size_t)row * ldc + col] = v;
        }
      }
    }
}

// ---------- split-K reduce: xdbl = sum partials; also emit bf16 dt_in ----------
__global__ __launch_bounds__(256) void k_xred(const float* __restrict__ part,
                                              float* __restrict__ xdbl,
                                              __hip_bfloat16* __restrict__ dtin) {
  int i = (blockIdx.x * 256 + threadIdx.x) * 4;
  float4 s = *reinterpret_cast<const float4*>(part + i);
#pragma unroll
  for (int p = 1; p < 8; p++) {
    const float4 v = *reinterpret_cast<const float4*>(part + (size_t)p * M * NXDBL + i);
    s.x += v.x; s.y += v.y; s.z += v.z; s.w += v.w;
  }
  *reinterpret_cast<float4*>(xdbl + i) = s;
  int c = i % NXDBL;
  if (c < DTR) {
    int m = i / NXDBL;
    __hip_bfloat16* dp = dtin + (size_t)m * DTR + c;
    dp[0] = __float2bfloat16(s.x);
    dp[1] = __float2bfloat16(s.y);
    dp[2] = __float2bfloat16(s.z);
    dp[3] = __float2bfloat16(s.w);
  }
}

// ---------- causal depthwise conv (width 4) + bias + silu, 8-wide ----------
__global__ __launch_bounds__(256) void k_conv8(const __hip_bfloat16* __restrict__ xz,
                                               const float* __restrict__ cwt,  // [DC][DI]
                                               const float* __restrict__ cb,
                                               __hip_bfloat16* __restrict__ xc) {
  const int ml = blockIdx.x;
  const int d0 = threadIdx.x * 8;
  const int l = ml & (SEQLEN - 1);
  float acc[8];
  {
    float4 b0 = *reinterpret_cast<const float4*>(cb + d0);
    float4 b1 = *reinterpret_cast<const float4*>(cb + d0 + 4);
    acc[0] = b0.x; acc[1] = b0.y; acc[2] = b0.z; acc[3] = b0.w;
    acc[4] = b1.x; acc[5] = b1.y; acc[6] = b1.z; acc[7] = b1.w;
  }
#pragma unroll
  for (int w = 0; w < DC; w++) {
    int li = l - 3 + w;
    if (li >= 0) {  // wave-uniform branch
      short8 xv = *reinterpret_cast<const short8*>(&xz[(size_t)(ml - 3 + w) * NXZ + d0]);
      float4 w0 = *reinterpret_cast<const float4*>(cwt + w * DI + d0);
      float4 w1 = *reinterpret_cast<const float4*>(cwt + w * DI + d0 + 4);
      float wf[8] = {w0.x, w0.y, w0.z, w0.w, w1.x, w1.y, w1.z, w1.w};
#pragma unroll
      for (int j = 0; j < 8; j++) {
        float x = __bfloat162float(__ushort_as_bfloat16((unsigned short)xv[j]));
        acc[j] = fmaf(x, wf[j], acc[j]);
      }
    }
  }
  unsigned short o[8];
#pragma unroll
  for (int j = 0; j < 8; j++)
    o[j] = __bfloat16_as_ushort(__float2bfloat16(acc[j] * fsig(acc[j])));
  *reinterpret_cast<short8*>(&xc[(size_t)ml * DI + d0]) = *reinterpret_cast<short8*>(o);
}

// ---------- scan pass 1: per-chunk local scan, f32x2 vector math ----------
template <int CLT>
__global__ __launch_bounds__(256) void k_scan1(const __hip_bfloat16* __restrict__ delta_b,
                                               const float* __restrict__ xdbl,
                                               const __hip_bfloat16* __restrict__ xc,
                                               const float* __restrict__ Aneg2,
                                               __hip_bfloat16* __restrict__ Pb,
                                               __hip_bfloat16* __restrict__ Sb) {
  const int tid = threadIdx.x;
  const int d = blockIdx.x * 256 + tid;
  const int c = blockIdx.y, b = blockIdx.z;
  const size_t row0 = (size_t)b * SEQLEN + (size_t)c * CLT;

  __shared__ float Bs[CLT][16];
  for (int e = tid * 4; e < CLT * 16; e += 1024) {
    int li = e >> 4, n0 = e & 15;
    *reinterpret_cast<float4*>(&Bs[li][n0]) =
        *reinterpret_cast<const float4*>(&xdbl[(row0 + li) * NXDBL + DTR + n0]);
  }

  f32x2 Ar2[8];
#pragma unroll
  for (int p = 0; p < 8; p++)
    Ar2[p] = *reinterpret_cast<const f32x2*>(&Aneg2[d * DS + 2 * p]);
  __syncthreads();

  f32x2 h2[8] = {};
  float sdelta = 0.f;
  size_t idx = row0 * DI + d;
  float nx_dt = __bfloat162float(delta_b[idx]);
  float nx_u = __bfloat162float(xc[idx]);
  for (int ls = 0; ls < CLT; ls++) {
    float delta = nx_dt;
    float u = nx_u;
    if (ls + 1 < CLT) {
      size_t idx2 = idx + DI;
      nx_dt = __bfloat162float(delta_b[idx2]);
      nx_u = __bfloat162float(xc[idx2]);
    }
    idx += DI;
    sdelta += delta;
    float du = delta * u;
    f32x2 delta2 = {delta, delta};
    f32x2 du2 = {du, du};
#pragma unroll
    for (int p = 0; p < 8; p++) {
      f32x2 arg = delta2 * Ar2[p];
      f32x2 dA = {fexp2(arg.x), fexp2(arg.y)};
      f32x2 t = du2 * *reinterpret_cast<const f32x2*>(&Bs[ls][2 * p]);
      h2[p] = __builtin_elementwise_fma(h2[p], dA, t);
    }
  }

  size_t base = (size_t)c * CS + ((size_t)b * DI + d) * DS;
  unsigned short sp[DS], ss[DS];
#pragma unroll
  for (int p = 0; p < 8; p++) {
    ss[2 * p] = __bfloat16_as_ushort(__float2bfloat16(h2[p].x));
    ss[2 * p + 1] = __bfloat16_as_ushort(__float2bfloat16(h2[p].y));
    sp[2 * p] = __bfloat16_as_ushort(__float2bfloat16(fexp2(Ar2[p].x * sdelta)));
    sp[2 * p + 1] = __bfloat16_as_ushort(__float2bfloat16(fexp2(Ar2[p].y * sdelta)));
  }
#pragma unroll
  for (int q = 0; q < 2; q++) {
    *reinterpret_cast<short8*>(&Sb[base + q * 8]) = *reinterpret_cast<short8*>(&ss[q * 8]);
    *reinterpret_cast<short8*>(&Pb[base + q * 8]) = *reinterpret_cast<short8*>(&sp[q * 8]);
  }
}

// ---------- scan pass 2: sequential scan over chunk transfer functions ----------
template <int NCHT>
__global__ __launch_bounds__(256) void k_scan2(const __hip_bfloat16* __restrict__ Pb,
                                               const __hip_bfloat16* __restrict__ Sb,
                                               __hip_bfloat16* __restrict__ Hin) {
  size_t t = (size_t)blockIdx.x * 256 + threadIdx.x;
  float h = 0.f;
  for (int c = 0; c < NCHT; c++) {
    size_t o = (size_t)c * CS + t;
    Hin[o] = __float2bfloat16(h);
    h = fmaf(__bfloat162float(Pb[o]), h, __bfloat162float(Sb[o]));
  }
}

// ---------- scan pass 3: re-scan with h_init, f32x2 vector math ----------
template <int CLT>
__global__ __launch_bounds__(256) void k_scan3(const __hip_bfloat16* __restrict__ delta_b,
                                               const float* __restrict__ xdbl,
                                               const __hip_bfloat16* __restrict__ xc,
                                               const __hip_bfloat16* __restrict__ xz,
                                               const float* __restrict__ Aneg2,
                                               const float* __restrict__ Dw,
                                               const __hip_bfloat16* __restrict__ Hin,
                                               __hip_bfloat16* __restrict__ yg) {
  const int tid = threadIdx.x;
  const int d = blockIdx.x * 256 + tid;
  const int c = blockIdx.y, b = blockIdx.z;
  const size_t row0 = (size_t)b * SEQLEN + (size_t)c * CLT;

  __shared__ float BCs[CLT][32];
  for (int e = tid * 8; e < CLT * 32; e += 2048) {
    int li = e >> 5, n0 = e & 31;
    const float* src = &xdbl[(row0 + li) * NXDBL + DTR + n0];
    *reinterpret_cast<float4*>(&BCs[li][n0]) = *reinterpret_cast<const float4*>(src);
    *reinterpret_cast<float4*>(&BCs[li][n0 + 4]) = *reinterpret_cast<const float4*>(src + 4);
  }

  f32x2 Ar2[8];
#pragma unroll
  for (int p = 0; p < 8; p++)
    Ar2[p] = *reinterpret_cast<const f32x2*>(&Aneg2[d * DS + 2 * p]);
  const float Dv = Dw[d];

  f32x2 h2[8];
  {
    size_t hbase = (size_t)c * CS + ((size_t)b * DI + d) * DS;
#pragma unroll
    for (int q = 0; q < 2; q++) {
      short8 hv = *reinterpret_cast<const short8*>(&Hin[hbase + q * 8]);
#pragma unroll
      for (int p = 0; p < 4; p++) {
        h2[q * 4 + p].x = __bfloat162float(__ushort_as_bfloat16((unsigned short)hv[2 * p]));
        h2[q * 4 + p].y = __bfloat162float(__ushort_as_bfloat16((unsigned short)hv[2 * p + 1]));
      }
    }
  }
  __syncthreads();

  size_t idx = row0 * DI + d;
  float nx_dt = __bfloat162float(delta_b[idx]);
  float nx_u = __bfloat162float(xc[idx]);
  float nx_z = __bfloat162float(xz[row0 * NXZ + DI + d]);
  for (int ls = 0; ls < CLT; ls++) {
    const size_t cur = idx;
    float delta = nx_dt;
    float u = nx_u;
    float zv = nx_z;
    if (ls + 1 < CLT) {
      size_t idx2 = idx + DI;
      nx_dt = __bfloat162float(delta_b[idx2]);
      nx_u = __bfloat162float(xc[idx2]);
      nx_z = __bfloat162float(xz[(row0 + ls + 1) * NXZ + DI + d]);
    }
    idx += DI;
    float du = delta * u;
    f32x2 delta2 = {delta, delta};
    f32x2 du2 = {du, du};
    f32x2 y20 = {0.f, 0.f}, y21 = {0.f, 0.f}, y22 = {0.f, 0.f}, y23 = {0.f, 0.f};
#pragma unroll
    for (int p = 0; p < 8; p++) {
      f32x2 arg = delta2 * Ar2[p];
      f32x2 dA = {fexp2(arg.x), fexp2(arg.y)};
      f32x2 t = du2 * *reinterpret_cast<const f32x2*>(&BCs[ls][2 * p]);
      h2[p] = __builtin_elementwise_fma(h2[p], dA, t);
      const f32x2 cv = *reinterpret_cast<const f32x2*>(&BCs[ls][16 + 2 * p]);
      if (p == 0 || p == 4) y20 = __builtin_elementwise_fma(h2[p], cv, y20);
      else if (p == 1 || p == 5) y21 = __builtin_elementwise_fma(h2[p], cv, y21);
      else if (p == 2 || p == 6) y22 = __builtin_elementwise_fma(h2[p], cv, y22);
      else y23 = __builtin_elementwise_fma(h2[p], cv, y23);
    }
    f32x2 ys = (y20 + y21) + (y22 + y23);
    float y = ys.x + ys.y;
    float out = (y + u * Dv) * (zv * fsig(zv));
    yg[cur] = __float2bfloat16(out);
  }
}

extern "C" void kernel_launch(void* const* d_in, const int* in_sizes, int n_in,
                              void* d_out, int out_size, void* d_ws, size_t ws_size,
                              hipStream_t stream) {
  const float* hs = (const float*)d_in[0];
  const float* w_in = (const float*)d_in[1];
  const float* conv_w = (const float*)d_in[2];
  const float* conv_b = (const float*)d_in[3];
  const float* w_xp = (const float*)d_in[4];
  const float* w_dt = (const float*)d_in[5];
  const float* dt_b = (const float*)d_in[6];
  const float* A_log = (const float*)d_in[7];
  const float* Dw = (const float*)d_in[8];
  const float* w_out = (const float*)d_in[9];
  float* out = (float*)d_out;

  char* ws = (char*)d_ws;
  size_t off = 0;
  auto alloc = [&](size_t bytes) {
    void* p = ws + off;
    off += (bytes + 255) & ~(size_t)255;
    return p;
  };

  __hip_bfloat16* hs_b   = (__hip_bfloat16*)alloc((size_t)M * DM * 2);     // [0, 16Mi)
  __hip_bfloat16* win_b  = (__hip_bfloat16*)alloc((size_t)NXZ * DM * 2);   // [16Mi, 24Mi)
  __hip_bfloat16* wxp_b  = (__hip_bfloat16*)alloc((size_t)NXDBL * DI * 2);
  __hip_bfloat16* wdt_b  = (__hip_bfloat16*)alloc((size_t)DI * DTR * 2);
  __hip_bfloat16* wout_b = (__hip_bfloat16*)alloc((size_t)DM * DI * 2);
  float*          Aneg2  = (float*)alloc((size_t)DI * DS * 4);
  float*          cwt    = (float*)alloc((size_t)DC * DI * 4);
  __hip_bfloat16* xz_b   = (__hip_bfloat16*)alloc((size_t)M * NXZ * 2);
  __hip_bfloat16* xc_b   = (__hip_bfloat16*)alloc((size_t)M * DI * 2);
  float*          xdbl   = (float*)alloc((size_t)M * NXDBL * 4);
  __hip_bfloat16* dtin_b = (__hip_bfloat16*)alloc((size_t)M * DTR * 2);
  __hip_bfloat16* delta_b= (__hip_bfloat16*)alloc((size_t)M * DI * 2);
  __hip_bfloat16* yg_b   = (__hip_bfloat16*)alloc((size_t)M * DI * 2);

  // CL=32 scan states (16Mi each): Pb/Sb fresh (only if ws allows), Hin in
  // the dead-after-in_proj alias region ws[0,24Mi).
  __hip_bfloat16* Pb32 = (__hip_bfloat16*)alloc((size_t)64 * CS * 2);
  __hip_bfloat16* Sb32 = (__hip_bfloat16*)alloc((size_t)64 * CS * 2);
  const bool cl32 = (off <= ws_size);

  // Alias region (dead after in_proj; xpart consumed by k_xred before scans):
  float* xpart = (float*)(ws + 0);
  __hip_bfloat16* Pb64  = (__hip_bfloat16*)(ws + 0);
  __hip_bfloat16* Sb64  = (__hip_bfloat16*)(ws + ((size_t)8 << 20));
  __hip_bfloat16* Hin   = (__hip_bfloat16*)(ws + ((size_t)16 << 20));
  __hip_bfloat16* Hin32 = (__hip_bfloat16*)(ws + 0);

  // 1) conversions + prep
  k_cvt5<<<(M * DM + NXZ * DM + NXDBL * DI + DI * DTR + DM * DI) / 2048, 256, 0, stream>>>(
      hs, M * DM, hs_b, w_in, NXZ * DM, win_b, w_xp, NXDBL * DI, wxp_b,
      w_dt, DI * DTR, wdt_b, w_out, DM * DI, wout_b);
  k_prep<<<(DI * DS + DI * DC + 255) / 256, 256, 0, stream>>>(A_log, Aneg2, conv_w, cwt);

  // 2) xz = hs @ in_proj_w^T  (M x 4096, bf16 out)
  k_gemmp<256, 1, false><<<dim3(NXZ / 256, M / 256), 512, 0, stream>>>(
      hs_b, DM, win_b, DM, xz_b, NXZ, DM);

  // 3) conv + silu -> x_conv (bf16)
  k_conv8<<<M, 256, 0, stream>>>(xz_b, cwt, conv_b, xc_b);

  // 4) x_dbl partials = x_conv @ x_proj_w^T, split-K x8
  k_gemm_dl<64, 96, 4><<<dim3(1, M / 64, 8), 256, 0, stream>>>(
      xc_b, DI, wxp_b, DI, xpart, NXDBL, DI / 8, nullptr);
  k_xred<<<(M * NXDBL) / 1024, 256, 0, stream>>>(xpart, xdbl, dtin_b);

  // 5) delta = softplus(dt_in @ dt_proj_w^T + dt_b)
  k_gemm_dl<64, 128, 2><<<dim3(DI / 128, M / 64), 256, 0, stream>>>(
      dtin_b, DTR, wdt_b, DTR, delta_b, DI, DTR, dt_b);

  // 6) chunked parallel scan: CL=32 (2048 blocks/pass) if workspace allows,
  //    else the verified CL=64 aliased layout. Branch is ws_size-deterministic.
  if (cl32) {
    k_scan1<32><<<dim3(DI / 256, 64, BATCH), 256, 0, stream>>>(delta_b, xdbl, xc_b,
                                                               Aneg2, Pb32, Sb32);
    k_scan2<64><<<(int)(CS / 256), 256, 0, stream>>>(Pb32, Sb32, Hin32);
    k_scan3<32><<<dim3(DI / 256, 64, BATCH), 256, 0, stream>>>(delta_b, xdbl, xc_b,
                                                               xz_b, Aneg2, Dw, Hin32, yg_b);
  } else {
    k_scan1<64><<<dim3(DI / 256, 32, BATCH), 256, 0, stream>>>(delta_b, xdbl, xc_b,
                                                               Aneg2, Pb64, Sb64);
    k_scan2<32><<<(int)(CS / 256), 256, 0, stream>>>(Pb64, Sb64, Hin);
    k_scan3<64><<<dim3(DI / 256, 32, BATCH), 256, 0, stream>>>(delta_b, xdbl, xc_b,
                                                               xz_b, Aneg2, Dw, Hin, yg_b);
  }

  // 7) out = y_gated @ out_proj_w^T  (M x 1024, fp32)
  k_gemmp<128, 0, true><<<dim3(DM / 128, M / 256), 512, 0, stream>>>(
      yg_b, DI, wout_b, DI, out, DM, DI);
}

// Round 18
// 286.181 us; speedup vs baseline: 1.0231x; 1.0231x over previous
//
#include <hip/hip_runtime.h>
#include <hip/hip_bf16.h>

constexpr int BATCH = 4, SEQLEN = 2048, DM = 1024, DI = 2048, DS = 16, DC = 4, DTR = 64;
constexpr int M = BATCH * SEQLEN;      // 8192
constexpr int NXZ = 2 * DI;            // 4096
constexpr int NXDBL = DTR + 2 * DS;    // 96
constexpr int CL = 64;                 // scan chunk length
constexpr int NCH = SEQLEN / CL;       // 32 chunks
constexpr size_t CS = (size_t)BATCH * DI * DS;  // per-chunk state stride (131072)
constexpr float L2E = 1.44269504088896f;

typedef __attribute__((ext_vector_type(8))) short short8;
typedef __attribute__((ext_vector_type(4))) float f32x4;
typedef __attribute__((ext_vector_type(2))) float f32x2;

__device__ __forceinline__ float fexp2(float x) { return __builtin_amdgcn_exp2f(x); }
__device__ __forceinline__ float frcp(float x) { return __builtin_amdgcn_rcpf(x); }
__device__ __forceinline__ float fsig(float z) {
  return frcp(1.f + fexp2(-L2E * z));
}
__device__ __forceinline__ float softplus_fast(float x) {
  return (x > 20.f) ? x
                    : 0.693147180559945f * __builtin_amdgcn_logf(1.f + fexp2(x * L2E));
}

// async global->LDS, 16B per lane; LDS dest wave-uniform base (+lane*16 HW).
__device__ __forceinline__ void load_lds16(const void* g, void* l) {
  __builtin_amdgcn_global_load_lds(
      (const __attribute__((address_space(1))) unsigned int*)g,
      (__attribute__((address_space(3))) unsigned int*)l, 16, 0, 0);
}

// ---------- merged 5-buffer f32 -> bf16 convert (8 elems/thread, 16B stores) ----------
__global__ __launch_bounds__(256) void k_cvt5(const float* __restrict__ p0, int n0, __hip_bfloat16* __restrict__ q0,
                                              const float* __restrict__ p1, int n1, __hip_bfloat16* __restrict__ q1,
                                              const float* __restrict__ p2, int n2, __hip_bfloat16* __restrict__ q2,
                                              const float* __restrict__ p3, int n3, __hip_bfloat16* __restrict__ q3,
                                              const float* __restrict__ p4, int n4, __hip_bfloat16* __restrict__ q4) {
  int i = (blockIdx.x * 256 + threadIdx.x) * 8;
  const float* s;
  __hip_bfloat16* d;
  if (i < n0) { s = p0; d = q0; }
  else if ((i -= n0) < n1) { s = p1; d = q1; }
  else if ((i -= n1) < n2) { s = p2; d = q2; }
  else if ((i -= n2) < n3) { s = p3; d = q3; }
  else if ((i -= n3) < n4) { s = p4; d = q4; }
  else return;
  float4 v0 = *reinterpret_cast<const float4*>(s + i);
  float4 v1 = *reinterpret_cast<const float4*>(s + i + 4);
  unsigned short o[8];
  o[0] = __bfloat16_as_ushort(__float2bfloat16(v0.x));
  o[1] = __bfloat16_as_ushort(__float2bfloat16(v0.y));
  o[2] = __bfloat16_as_ushort(__float2bfloat16(v0.z));
  o[3] = __bfloat16_as_ushort(__float2bfloat16(v0.w));
  o[4] = __bfloat16_as_ushort(__float2bfloat16(v1.x));
  o[5] = __bfloat16_as_ushort(__float2bfloat16(v1.y));
  o[6] = __bfloat16_as_ushort(__float2bfloat16(v1.z));
  o[7] = __bfloat16_as_ushort(__float2bfloat16(v1.w));
  *reinterpret_cast<short8*>(d + i) = *reinterpret_cast<short8*>(o);
}

// ---------- prep: A2 = -exp(A_log)*log2e  AND conv-w transpose, one launch ----------
__global__ __launch_bounds__(256) void k_prep(const float* __restrict__ alog,
                                              float* __restrict__ an,
                                              const float* __restrict__ cw,
                                              float* __restrict__ cwt) {
  int i = blockIdx.x * 256 + threadIdx.x;
  if (i < DI * DS) {
    an[i] = -__expf(alog[i]) * L2E;
  } else {
    int j = i - DI * DS;
    if (j < DI * DC) {
      int d = j >> 2, w = j & 3;
      cwt[w * DI + d] = cw[j];
    }
  }
}

// ---------- pipelined 256xBN BK=64 bf16 NT GEMM, stages-at-top (verified best) ----------
template <int BN, int OUTMODE, bool SWZ>  // OUTMODE: 0=f32, 1=bf16
__global__ __launch_bounds__(512, 2) void k_gemmp(const __hip_bfloat16* __restrict__ A, int lda,
                                                  const __hip_bfloat16* __restrict__ Bm, int ldb,
                                                  void* __restrict__ Cp, int ldc, int K) {
  constexpr int BK = 64;
  constexpr int ASLOT = 16384;
  constexpr int BSLOT = BN * BK;
  constexpr int FN = (BN / 4) / 16;
  constexpr int BBASE = 2 * ASLOT;

  const int tid = threadIdx.x;
  const int wid = tid >> 6, l = tid & 63;
  const int wr = wid >> 2, wc = wid & 3;

  int bx = blockIdx.x, by = blockIdx.y;
  if constexpr (SWZ) {
    const int gx = gridDim.x;
    int nlin = by * gx + bx;
    const int nwg = gx * gridDim.y;
    nlin = (nlin & 7) * (nwg >> 3) + (nlin >> 3);
    by = nlin / gx; bx = nlin % gx;
  }
  const int bm0 = by * 256, bn0 = bx * BN;
  const int NT = K / BK;

  __shared__ short LDS[2 * (ASLOT + BSLOT)];

  const int gc8 = (l & 7) ^ ((l >> 3) & 7);
  const __hip_bfloat16* Abase = A + (size_t)(bm0 + wid * 8 + (l >> 3)) * lda + gc8 * 8;
  const __hip_bfloat16* Bbase = Bm + (size_t)(bn0 + wid * 8 + (l >> 3)) * ldb + gc8 * 8;
  const int wslot = wid * 512;

  const int c8k0 = ((l >> 4) ^ (l & 7)) * 8;
  const int c8k1 = ((4 + (l >> 4)) ^ (l & 7)) * 8;
  const int aoff0 = wr * 8192 + (l & 15) * 64;
  const int boff0 = BBASE + wc * (BN / 4) * 64 + (l & 15) * 64;

  f32x4 acc[8][FN] = {};

  auto stageA = [&](int s, int kt) {
#pragma unroll
    for (int g = 0; g < 4; g++)
      load_lds16(Abase + (size_t)(g * 64) * lda + kt * BK,
                 &LDS[s * ASLOT + g * 4096 + wslot]);
  };
  auto stageB = [&](int s, int kt) {
#pragma unroll
    for (int g = 0; g < BN / 64; g++)
      load_lds16(Bbase + (size_t)(g * 64) * ldb + kt * BK,
                 &LDS[BBASE + s * BSLOT + g * 4096 + wslot]);
  };

  stageA(0, 0); stageB(0, 0);

  for (int t = 0; t < NT; t++) {
    const int d = t & 1;
    asm volatile("s_waitcnt vmcnt(0)" ::: "memory");
    __builtin_amdgcn_s_barrier();
    if (t + 1 < NT) { stageA(d ^ 1, t + 1); stageB(d ^ 1, t + 1); }

    const int adb = d * ASLOT + aoff0;
    const int bdb = d * BSLOT + boff0;
    short8 a0[4][2], a1[4][2], b[FN][2];
#pragma unroll
    for (int i = 0; i < 4; i++) {
      a0[i][0] = *reinterpret_cast<const short8*>(&LDS[adb + i * 1024 + c8k0]);
      a0[i][1] = *reinterpret_cast<const short8*>(&LDS[adb + i * 1024 + c8k1]);
    }
#pragma unroll
    for (int j = 0; j < FN; j++) {
      b[j][0] = *reinterpret_cast<const short8*>(&LDS[bdb + j * 1024 + c8k0]);
      b[j][1] = *reinterpret_cast<const short8*>(&LDS[bdb + j * 1024 + c8k1]);
    }
#pragma unroll
    for (int i = 0; i < 4; i++) {
      a1[i][0] = *reinterpret_cast<const short8*>(&LDS[adb + (4 + i) * 1024 + c8k0]);
      a1[i][1] = *reinterpret_cast<const short8*>(&LDS[adb + (4 + i) * 1024 + c8k1]);
    }
#pragma unroll
    for (int i = 0; i < 4; i++)
#pragma unroll
      for (int j = 0; j < FN; j++)
#pragma unroll
        for (int ks = 0; ks < 2; ks++) {
          acc[i][j] = __builtin_amdgcn_mfma_f32_16x16x32_bf16(a0[i][ks], b[j][ks], acc[i][j], 0, 0, 0);
          acc[4 + i][j] = __builtin_amdgcn_mfma_f32_16x16x32_bf16(a1[i][ks], b[j][ks], acc[4 + i][j], 0, 0, 0);
        }
  }

  const int crow0 = bm0 + wr * 128 + (l >> 4) * 4;
  const int ccol0 = bn0 + wc * (BN / 4) + (l & 15);
#pragma unroll
  for (int im = 0; im < 8; im++)
#pragma unroll
    for (int jn = 0; jn < FN; jn++) {
      const int col = ccol0 + jn * 16;
#pragma unroll
      for (int r = 0; r < 4; r++) {
        const int row = crow0 + im * 16 + r;
        float v = acc[im][jn][r];
        if constexpr (OUTMODE == 0)
          reinterpret_cast<float*>(Cp)[(size_t)row * ldc + col] = v;
        else
          reinterpret_cast<__hip_bfloat16*>(Cp)[(size_t)row * ldc + col] = __float2bfloat16(v);
      }
    }
}

// ---------- bf16 NT GEMM, m97 structure ----------
template <int BM, int BN, int OUTMODE>
__global__ __launch_bounds__(256) void k_gemm_dl(const __hip_bfloat16* __restrict__ A, int lda,
                                                 const __hip_bfloat16* __restrict__ Bm, int ldb,
                                                 void* __restrict__ Cp, int ldc, int K,
                                                 const float* __restrict__ bias) {
  constexpr int BK = 32;
  constexpr int WM = BM / 2, WN = BN / 2;
  constexpr int FM = WM / 16, FN = WN / 16;

  const int tid = threadIdx.x;
  const int wid = tid >> 6, lane = tid & 63;
  const int wm = wid >> 1, wn = wid & 1;
  const int bm0 = blockIdx.y * BM, bn0 = blockIdx.x * BN;
  int kz = 0;
  if constexpr (OUTMODE == 4) kz = blockIdx.z;

  __shared__ short As[BM * BK];
  __shared__ short Bs[BN * BK];

  f32x4 acc[FM][FN] = {};

  const int lrow = lane & 15;
  const int lk = (lane >> 4) * 8;
  const int srow = wid * 16 + (lane >> 2);
  const int scol = (lane & 3) * 8;

  const __hip_bfloat16* Ag = &A[(size_t)(bm0 + srow) * lda + scol + (size_t)kz * K];
  const __hip_bfloat16* Bg = &Bm[(size_t)(bn0 + srow) * ldb + scol + (size_t)kz * K];

  for (int k0 = 0; k0 < K; k0 += BK) {
    __syncthreads();
#pragma unroll
    for (int i = 0; i < (BM + 63) / 64; i++)
      load_lds16(Ag + (size_t)i * 64 * lda + k0, &As[(i * 64 + wid * 16) * BK]);
#pragma unroll
    for (int i = 0; i < (BN + 63) / 64; i++)
      if ((BN % 64 == 0) || (i * 64 + wid * 16 < BN))
        load_lds16(Bg + (size_t)i * 64 * ldb + k0, &Bs[(i * 64 + wid * 16) * BK]);
    __syncthreads();

    short8 af[FM], bf[FN];
#pragma unroll
    for (int i = 0; i < FM; i++)
      af[i] = *reinterpret_cast<const short8*>(&As[(wm * WM + i * 16 + lrow) * BK + lk]);
#pragma unroll
    for (int j = 0; j < FN; j++)
      bf[j] = *reinterpret_cast<const short8*>(&Bs[(wn * WN + j * 16 + lrow) * BK + lk]);
#pragma unroll
    for (int i = 0; i < FM; i++)
#pragma unroll
      for (int j = 0; j < FN; j++)
        acc[i][j] = __builtin_amdgcn_mfma_f32_16x16x32_bf16(af[i], bf[j], acc[i][j], 0, 0, 0);
  }

  const int crow0 = bm0 + wm * WM + (lane >> 4) * 4;
  const int ccol0 = bn0 + wn * WN + lrow;
#pragma unroll
  for (int i = 0; i < FM; i++)
#pragma unroll
    for (int j = 0; j < FN; j++) {
      const int col = ccol0 + j * 16;
      float bv = 0.f;
      if constexpr (OUTMODE == 2) bv = bias[col];
#pragma unroll
      for (int r = 0; r < 4; r++) {
        const int row = crow0 + i * 16 + r;
        float v = acc[i][j][r];
        if constexpr (OUTMODE == 0) {
          reinterpret_cast<float*>(Cp)[(size_t)row * ldc + col] = v;
        } else if constexpr (OUTMODE == 2) {
          reinterpret_cast<__hip_bfloat16*>(Cp)[(size_t)row * ldc + col] =
              __float2bfloat16(softplus_fast(v + bv));
        } else {  // 4: split-K partial
          reinterpret_cast<float*>(Cp)[(size_t)kz * M * NXDBL + (size_t)row * ldc + col] = v;
        }
      }
    }
}

// ---------- split-K reduce: xdbl = sum partials; also emit bf16 dt_in ----------
__global__ __launch_bounds__(256) void k_xred(const float* __restrict__ part,
                                              float* __restrict__ xdbl,
                                              __hip_bfloat16* __restrict__ dtin) {
  int i = (blockIdx.x * 256 + threadIdx.x) * 4;
  float4 s = *reinterpret_cast<const float4*>(part + i);
#pragma unroll
  for (int p = 1; p < 8; p++) {
    const float4 v = *reinterpret_cast<const float4*>(part + (size_t)p * M * NXDBL + i);
    s.x += v.x; s.y += v.y; s.z += v.z; s.w += v.w;
  }
  *reinterpret_cast<float4*>(xdbl + i) = s;
  int c = i % NXDBL;
  if (c < DTR) {
    int m = i / NXDBL;
    __hip_bfloat16* dp = dtin + (size_t)m * DTR + c;
    dp[0] = __float2bfloat16(s.x);
    dp[1] = __float2bfloat16(s.y);
    dp[2] = __float2bfloat16(s.z);
    dp[3] = __float2bfloat16(s.w);
  }
}

// ---------- causal depthwise conv (width 4) + bias + silu, 8-wide ----------
__global__ __launch_bounds__(256) void k_conv8(const __hip_bfloat16* __restrict__ xz,
                                               const float* __restrict__ cwt,  // [DC][DI]
                                               const float* __restrict__ cb,
                                               __hip_bfloat16* __restrict__ xc) {
  const int ml = blockIdx.x;
  const int d0 = threadIdx.x * 8;
  const int l = ml & (SEQLEN - 1);
  float acc[8];
  {
    float4 b0 = *reinterpret_cast<const float4*>(cb + d0);
    float4 b1 = *reinterpret_cast<const float4*>(cb + d0 + 4);
    acc[0] = b0.x; acc[1] = b0.y; acc[2] = b0.z; acc[3] = b0.w;
    acc[4] = b1.x; acc[5] = b1.y; acc[6] = b1.z; acc[7] = b1.w;
  }
#pragma unroll
  for (int w = 0; w < DC; w++) {
    int li = l - 3 + w;
    if (li >= 0) {  // wave-uniform branch
      short8 xv = *reinterpret_cast<const short8*>(&xz[(size_t)(ml - 3 + w) * NXZ + d0]);
      float4 w0 = *reinterpret_cast<const float4*>(cwt + w * DI + d0);
      float4 w1 = *reinterpret_cast<const float4*>(cwt + w * DI + d0 + 4);
      float wf[8] = {w0.x, w0.y, w0.z, w0.w, w1.x, w1.y, w1.z, w1.w};
#pragma unroll
      for (int j = 0; j < 8; j++) {
        float x = __bfloat162float(__ushort_as_bfloat16((unsigned short)xv[j]));
        acc[j] = fmaf(x, wf[j], acc[j]);
      }
    }
  }
  unsigned short o[8];
#pragma unroll
  for (int j = 0; j < 8; j++)
    o[j] = __bfloat16_as_ushort(__float2bfloat16(acc[j] * fsig(acc[j])));
  *reinterpret_cast<short8*>(&xc[(size_t)ml * DI + d0]) = *reinterpret_cast<short8*>(o);
}

// ---------- scan pass 1: per-chunk local scan, f32x2 vector math ----------
__global__ __launch_bounds__(256) void k_scan1(const __hip_bfloat16* __restrict__ delta_b,
                                               const float* __restrict__ xdbl,
                                               const __hip_bfloat16* __restrict__ xc,
                                               const float* __restrict__ Aneg2,
                                               __hip_bfloat16* __restrict__ Pb,
                                               __hip_bfloat16* __restrict__ Sb) {
  const int tid = threadIdx.x;
  const int d = blockIdx.x * 256 + tid;
  const int c = blockIdx.y, b = blockIdx.z;
  const size_t row0 = (size_t)b * SEQLEN + (size_t)c * CL;

  __shared__ float Bs[CL][16];
  {
    int i = tid * 4;
    int li = i >> 4, n0 = i & 15;
    const float* src = &xdbl[(row0 + li) * NXDBL + DTR + n0];
    *reinterpret_cast<float4*>(&Bs[li][n0]) = *reinterpret_cast<const float4*>(src);
  }

  f32x2 Ar2[8];
#pragma unroll
  for (int p = 0; p < 8; p++)
    Ar2[p] = *reinterpret_cast<const f32x2*>(&Aneg2[d * DS + 2 * p]);
  __syncthreads();

  f32x2 h2[8] = {};
  float sdelta = 0.f;
  size_t idx = row0 * DI + d;
  float nx_dt = __bfloat162float(delta_b[idx]);
  float nx_u = __bfloat162float(xc[idx]);
  for (int ls = 0; ls < CL; ls++) {
    float delta = nx_dt;
    float u = nx_u;
    if (ls + 1 < CL) {
      size_t idx2 = idx + DI;
      nx_dt = __bfloat162float(delta_b[idx2]);
      nx_u = __bfloat162float(xc[idx2]);
    }
    idx += DI;
    sdelta += delta;
    float du = delta * u;
    f32x2 delta2 = {delta, delta};
    f32x2 du2 = {du, du};
#pragma unroll
    for (int p = 0; p < 8; p++) {
      f32x2 arg = delta2 * Ar2[p];
      f32x2 dA = {fexp2(arg.x), fexp2(arg.y)};
      f32x2 t = du2 * *reinterpret_cast<const f32x2*>(&Bs[ls][2 * p]);
      h2[p] = __builtin_elementwise_fma(h2[p], dA, t);
    }
  }

  size_t base = (size_t)c * CS + ((size_t)b * DI + d) * DS;
  unsigned short sp[DS], ss[DS];
#pragma unroll
  for (int p = 0; p < 8; p++) {
    ss[2 * p] = __bfloat16_as_ushort(__float2bfloat16(h2[p].x));
    ss[2 * p + 1] = __bfloat16_as_ushort(__float2bfloat16(h2[p].y));
    sp[2 * p] = __bfloat16_as_ushort(__float2bfloat16(fexp2(Ar2[p].x * sdelta)));
    sp[2 * p + 1] = __bfloat16_as_ushort(__float2bfloat16(fexp2(Ar2[p].y * sdelta)));
  }
#pragma unroll
  for (int q = 0; q < 2; q++) {
    *reinterpret_cast<short8*>(&Sb[base + q * 8]) = *reinterpret_cast<short8*>(&ss[q * 8]);
    *reinterpret_cast<short8*>(&Pb[base + q * 8]) = *reinterpret_cast<short8*>(&sp[q * 8]);
  }
}

// ---------- scan pass 2: sequential scan over chunk transfer functions ----------
__global__ __launch_bounds__(256) void k_scan2(const __hip_bfloat16* __restrict__ Pb,
                                               const __hip_bfloat16* __restrict__ Sb,
                                               __hip_bfloat16* __restrict__ Hin) {
  size_t t = (size_t)blockIdx.x * 256 + threadIdx.x;
  float h = 0.f;
  for (int c = 0; c < NCH; c++) {
    size_t o = (size_t)c * CS + t;
    Hin[o] = __float2bfloat16(h);
    h = fmaf(__bfloat162float(Pb[o]), h, __bfloat162float(Sb[o]));
  }
}

// ---------- scan pass 3: re-scan with h_init, f32x2 vector math ----------
__global__ __launch_bounds__(256) void k_scan3(const __hip_bfloat16* __restrict__ delta_b,
                                               const float* __restrict__ xdbl,
                                               const __hip_bfloat16* __restrict__ xc,
                                               const __hip_bfloat16* __restrict__ xz,
                                               const float* __restrict__ Aneg2,
                                               const float* __restrict__ Dw,
                                               const __hip_bfloat16* __restrict__ Hin,
                                               __hip_bfloat16* __restrict__ yg) {
  const int tid = threadIdx.x;
  const int d = blockIdx.x * 256 + tid;
  const int c = blockIdx.y, b = blockIdx.z;
  const size_t row0 = (size_t)b * SEQLEN + (size_t)c * CL;

  __shared__ float BCs[CL][32];
  {
    int i = tid * 8;
    int li = i >> 5, n0 = i & 31;
    const float* src = &xdbl[(row0 + li) * NXDBL + DTR + n0];
    *reinterpret_cast<float4*>(&BCs[li][n0]) = *reinterpret_cast<const float4*>(src);
    *reinterpret_cast<float4*>(&BCs[li][n0 + 4]) = *reinterpret_cast<const float4*>(src + 4);
  }

  f32x2 Ar2[8];
#pragma unroll
  for (int p = 0; p < 8; p++)
    Ar2[p] = *reinterpret_cast<const f32x2*>(&Aneg2[d * DS + 2 * p]);
  const float Dv = Dw[d];

  f32x2 h2[8];
  {
    size_t hbase = (size_t)c * CS + ((size_t)b * DI + d) * DS;
#pragma unroll
    for (int q = 0; q < 2; q++) {
      short8 hv = *reinterpret_cast<const short8*>(&Hin[hbase + q * 8]);
#pragma unroll
      for (int p = 0; p < 4; p++) {
        h2[q * 4 + p].x = __bfloat162float(__ushort_as_bfloat16((unsigned short)hv[2 * p]));
        h2[q * 4 + p].y = __bfloat162float(__ushort_as_bfloat16((unsigned short)hv[2 * p + 1]));
      }
    }
  }
  __syncthreads();

  size_t idx = row0 * DI + d;
  float nx_dt = __bfloat162float(delta_b[idx]);
  float nx_u = __bfloat162float(xc[idx]);
  float nx_z = __bfloat162float(xz[row0 * NXZ + DI + d]);
  for (int ls = 0; ls < CL; ls++) {
    const size_t cur = idx;
    float delta = nx_dt;
    float u = nx_u;
    float zv = nx_z;
    if (ls + 1 < CL) {
      size_t idx2 = idx + DI;
      nx_dt = __bfloat162float(delta_b[idx2]);
      nx_u = __bfloat162float(xc[idx2]);
      nx_z = __bfloat162float(xz[(row0 + ls + 1) * NXZ + DI + d]);
    }
    idx += DI;
    float du = delta * u;
    f32x2 delta2 = {delta, delta};
    f32x2 du2 = {du, du};
    f32x2 y20 = {0.f, 0.f}, y21 = {0.f, 0.f}, y22 = {0.f, 0.f}, y23 = {0.f, 0.f};
#pragma unroll
    for (int p = 0; p < 8; p++) {
      f32x2 arg = delta2 * Ar2[p];
      f32x2 dA = {fexp2(arg.x), fexp2(arg.y)};
      f32x2 t = du2 * *reinterpret_cast<const f32x2*>(&BCs[ls][2 * p]);
      h2[p] = __builtin_elementwise_fma(h2[p], dA, t);
      const f32x2 cv = *reinterpret_cast<const f32x2*>(&BCs[ls][16 + 2 * p]);
      if (p == 0 || p == 4) y20 = __builtin_elementwise_fma(h2[p], cv, y20);
      else if (p == 1 || p == 5) y21 = __builtin_elementwise_fma(h2[p], cv, y21);
      else if (p == 2 || p == 6) y22 = __builtin_elementwise_fma(h2[p], cv, y22);
      else y23 = __builtin_elementwise_fma(h2[p], cv, y23);
    }
    f32x2 ys = (y20 + y21) + (y22 + y23);
    float y = ys.x + ys.y;
    float out = (y + u * Dv) * (zv * fsig(zv));
    yg[cur] = __float2bfloat16(out);
  }
}

extern "C" void kernel_launch(void* const* d_in, const int* in_sizes, int n_in,
                              void* d_out, int out_size, void* d_ws, size_t ws_size,
                              hipStream_t stream) {
  const float* hs = (const float*)d_in[0];
  const float* w_in = (const float*)d_in[1];
  const float* conv_w = (const float*)d_in[2];
  const float* conv_b = (const float*)d_in[3];
  const float* w_xp = (const float*)d_in[4];
  const float* w_dt = (const float*)d_in[5];
  const float* dt_b = (const float*)d_in[6];
  const float* A_log = (const float*)d_in[7];
  const float* Dw = (const float*)d_in[8];
  const float* w_out = (const float*)d_in[9];
  float* out = (float*)d_out;

  char* ws = (char*)d_ws;
  size_t off = 0;
  auto alloc = [&](size_t bytes) {
    void* p = ws + off;
    off += (bytes + 255) & ~(size_t)255;
    return p;
  };

  __hip_bfloat16* hs_b   = (__hip_bfloat16*)alloc((size_t)M * DM * 2);     // [0, 16Mi)
  __hip_bfloat16* win_b  = (__hip_bfloat16*)alloc((size_t)NXZ * DM * 2);   // [16Mi, 24Mi)
  __hip_bfloat16* wxp_b  = (__hip_bfloat16*)alloc((size_t)NXDBL * DI * 2);
  __hip_bfloat16* wdt_b  = (__hip_bfloat16*)alloc((size_t)DI * DTR * 2);
  __hip_bfloat16* wout_b = (__hip_bfloat16*)alloc((size_t)DM * DI * 2);
  float*          Aneg2  = (float*)alloc((size_t)DI * DS * 4);
  float*          cwt    = (float*)alloc((size_t)DC * DI * 4);
  __hip_bfloat16* xz_b   = (__hip_bfloat16*)alloc((size_t)M * NXZ * 2);
  __hip_bfloat16* xc_b   = (__hip_bfloat16*)alloc((size_t)M * DI * 2);
  float*          xdbl   = (float*)alloc((size_t)M * NXDBL * 4);
  __hip_bfloat16* dtin_b = (__hip_bfloat16*)alloc((size_t)M * DTR * 2);
  __hip_bfloat16* delta_b= (__hip_bfloat16*)alloc((size_t)M * DI * 2);
  __hip_bfloat16* yg_b   = (__hip_bfloat16*)alloc((size_t)M * DI * 2);

  // Dead-after-in_proj alias region ws[0, 24Mi):
  //  - x_proj split-K partials: 8 x M x 96 f32 = 24Mi (used before scans)
  //  - scan chunk states Pb/Sb/Hin (bf16, 8Mi each; each pass rewrites fully)
  float* xpart = (float*)(ws + 0);
  __hip_bfloat16* Pb  = (__hip_bfloat16*)(ws + 0);
  __hip_bfloat16* Sb  = (__hip_bfloat16*)(ws + ((size_t)8 << 20));
  __hip_bfloat16* Hin = (__hip_bfloat16*)(ws + ((size_t)16 << 20));

  // 1) conversions + prep (single merged cvt launch)
  k_cvt5<<<(M * DM + NXZ * DM + NXDBL * DI + DI * DTR + DM * DI) / 2048, 256, 0, stream>>>(
      hs, M * DM, hs_b, w_in, NXZ * DM, win_b, w_xp, NXDBL * DI, wxp_b,
      w_dt, DI * DTR, wdt_b, w_out, DM * DI, wout_b);
  k_prep<<<(DI * DS + DI * DC + 255) / 256, 256, 0, stream>>>(A_log, Aneg2, conv_w, cwt);

  // 2) xz = hs @ in_proj_w^T  (M x 4096, bf16 out) — 256x256, stages-at-top
  k_gemmp<256, 1, false><<<dim3(NXZ / 256, M / 256), 512, 0, stream>>>(
      hs_b, DM, win_b, DM, xz_b, NXZ, DM);

  // 3) conv + silu -> x_conv (bf16), 8-wide vectorized
  k_conv8<<<M, 256, 0, stream>>>(xz_b, cwt, conv_b, xc_b);

  // 4) x_dbl partials = x_conv @ x_proj_w^T, split-K x8 (per-slice K=256)
  k_gemm_dl<64, 96, 4><<<dim3(1, M / 64, 8), 256, 0, stream>>>(
      xc_b, DI, wxp_b, DI, xpart, NXDBL, DI / 8, nullptr);
  // 4b) reduce partials -> xdbl f32 + dt_in bf16
  k_xred<<<(M * NXDBL) / 1024, 256, 0, stream>>>(xpart, xdbl, dtin_b);

  // 5) delta = softplus(dt_in @ dt_proj_w^T + dt_b)  (M x 2048, bf16)
  k_gemm_dl<64, 128, 2><<<dim3(DI / 128, M / 64), 256, 0, stream>>>(
      dtin_b, DTR, wdt_b, DTR, delta_b, DI, DTR, dt_b);

  // 6) chunked parallel scan (CL=64, NCH=32), f32x2 vector math
  k_scan1<<<dim3(DI / 256, NCH, BATCH), 256, 0, stream>>>(delta_b, xdbl, xc_b,
                                                          Aneg2, Pb, Sb);
  k_scan2<<<(int)(CS / 256), 256, 0, stream>>>(Pb, Sb, Hin);
  k_scan3<<<dim3(DI / 256, NCH, BATCH), 256, 0, stream>>>(delta_b, xdbl, xc_b,
                                                          xz_b, Aneg2, Dw, Hin, yg_b);

  // 7) out = y_gated @ out_proj_w^T  (M x 1024, fp32) — 256x128, swizzled
  k_gemmp<128, 0, true><<<dim3(DM / 128, M / 256), 512, 0, stream>>>(
      yg_b, DI, wout_b, DI, out, DM, DI);
}